// Round 16
// baseline (176.865 us; speedup 1.0000x reference)
//
#include <hip/hip_runtime.h>
#include <hip/hip_bf16.h>
#include <math.h>

#define NEXP 64
#define TOPK 8

// compare-exchange, descending, strict (> only): equal values never swap
#define CE(VA, IA, VB, IB)                                        \
    {                                                             \
        bool s_ = ((VB) > (VA));                                  \
        float tv_ = (VA); int ti_ = (IA);                         \
        VA = s_ ? (VB) : (VA); IA = s_ ? (IB) : (IA);             \
        VB = s_ ? tv_  : (VB); IB = s_ ? ti_  : (IB);             \
    }

// Batcher odd-even merge sort for 8 (19 CE), descending
#define SORT8(V0,I0,V1,I1,V2,I2,V3,I3,V4,I4,V5,I5,V6,I6,V7,I7)        \
    CE(V0,I0,V1,I1) CE(V2,I2,V3,I3) CE(V4,I4,V5,I5) CE(V6,I6,V7,I7)   \
    CE(V0,I0,V2,I2) CE(V1,I1,V3,I3) CE(V4,I4,V6,I6) CE(V5,I5,V7,I7)   \
    CE(V1,I1,V2,I2) CE(V5,I5,V6,I6)                                   \
    CE(V0,I0,V4,I4) CE(V1,I1,V5,I5) CE(V2,I2,V6,I6) CE(V3,I3,V7,I7)   \
    CE(V2,I2,V4,I4) CE(V3,I3,V5,I5)                                   \
    CE(V1,I1,V2,I2) CE(V3,I3,V4,I4) CE(V5,I5,V6,I6)

// winner/loser step: VA <- max(VA,VB), rm <- max(rm, loser)
#define MTOP(VA, IA, VB, IB)                                      \
    {                                                             \
        bool s_ = ((VB) > (VA));                                  \
        float lo_ = s_ ? (VA) : (VB);                             \
        VA = s_ ? (VB) : (VA); IA = s_ ? (IB) : (IA);             \
        rm = fmaxf(rm, lo_);                                      \
    }

// bitonic clean of a descending-bitonic 8 (12 CE)
#define BITONIC8(V0,I0,V1,I1,V2,I2,V3,I3,V4,I4,V5,I5,V6,I6,V7,I7)     \
    CE(V0,I0,V4,I4) CE(V1,I1,V5,I5) CE(V2,I2,V6,I6) CE(V3,I3,V7,I7)   \
    CE(V0,I0,V2,I2) CE(V1,I1,V3,I3) CE(V4,I4,V6,I6) CE(V5,I5,V7,I7)   \
    CE(V0,I0,V1,I1) CE(V2,I2,V3,I3) CE(V4,I4,V5,I5) CE(V6,I6,V7,I7)

// cross-lane merge: partner's sorted-8 reversed feeds the bitonic merge
#define MERGE_LEVEL(MASK)                                                     \
    {                                                                         \
        float b0_ = __shfl_xor(e0, MASK), b1_ = __shfl_xor(e1, MASK);         \
        float b2_ = __shfl_xor(e2, MASK), b3_ = __shfl_xor(e3, MASK);         \
        float b4_ = __shfl_xor(e4, MASK), b5_ = __shfl_xor(e5, MASK);         \
        float b6_ = __shfl_xor(e6, MASK), b7_ = __shfl_xor(e7, MASK);         \
        int   j0_ = __shfl_xor(i0, MASK), j1_ = __shfl_xor(i1, MASK);         \
        int   j2_ = __shfl_xor(i2, MASK), j3_ = __shfl_xor(i3, MASK);         \
        int   j4_ = __shfl_xor(i4, MASK), j5_ = __shfl_xor(i5, MASK);         \
        int   j6_ = __shfl_xor(i6, MASK), j7_ = __shfl_xor(i7, MASK);         \
        float pr_ = __shfl_xor(rm, MASK);                                     \
        rm = fmaxf(rm, pr_);                                                  \
        MTOP(e0,i0, b7_,j7_) MTOP(e1,i1, b6_,j6_)                             \
        MTOP(e2,i2, b5_,j5_) MTOP(e3,i3, b4_,j4_)                             \
        MTOP(e4,i4, b3_,j3_) MTOP(e5,i5, b2_,j2_)                             \
        MTOP(e6,i6, b1_,j1_) MTOP(e7,i7, b0_,j0_)                             \
        BITONIC8(e0,i0, e1,i1, e2,i2, e3,i3, e4,i4, e5,i5, e6,i6, e7,i7)      \
    }

#define SLOW_STAGE(TV, TI)                                \
    {                                                     \
        bool gt = (x > TV);                               \
        float nv = gt ? x  : TV;                          \
        float cv = gt ? TV : x;                           \
        int   ni = gt ? xi : TI;                          \
        int   ci = gt ? TI : xi;                          \
        TV = nv; x = cv; TI = ni; xi = ci;                \
    }

#define TIESWAP(CA, IA, CB, IB)                           \
    {                                                     \
        bool sw = (CA == CB) && (IA > IB);                \
        int tt = IA;                                      \
        IA = sw ? IB : IA;                                \
        IB = sw ? tt : IB;                                \
    }
#define TIEPASS                                           \
    TIESWAP(s0, si0, s1, si1)                             \
    TIESWAP(s1, si1, s2, si2)                             \
    TIESWAP(s2, si2, s3, si3)                             \
    TIESWAP(s3, si3, s4, si4)                             \
    TIESWAP(s4, si4, s5, si5)                             \
    TIESWAP(s5, si5, s6, si6)                             \
    TIESWAP(s6, si6, s7, si7)                             \
    TIESWAP(s7, si7, s8, si8)                             \
    TIESWAP(s8, si8, s9, si9)

// Full r13 selection + output for one 16-row batch (quad-owned data).
// Called by ALL lanes (shuffles need full quads); invalid rows carry zeros
// and exit after the shuffle section.
__device__ __forceinline__ void process_rows(
    float4 a0, float4 a1, float4 a2, float4 a3,
    int q, int row, bool ok,
    const float* __restrict__ logits,
    float* __restrict__ w_out, float* __restrict__ id_out)
{
    // element indices: chunk i covers i*16 + q*4 + {0..3}
    const int bq = q * 4;
    float e0 = a0.x,  e1 = a0.y,  e2 = a0.z,  e3 = a0.w;
    float e4 = a1.x,  e5 = a1.y,  e6 = a1.z,  e7 = a1.w;
    float e8 = a2.x,  e9 = a2.y,  e10 = a2.z, e11 = a2.w;
    float e12 = a3.x, e13 = a3.y, e14 = a3.z, e15 = a3.w;
    int i0 = bq + 0,       i1 = bq + 1,       i2 = bq + 2,       i3 = bq + 3;
    int i4 = 16 + bq + 0,  i5 = 16 + bq + 1,  i6 = 16 + bq + 2,  i7 = 16 + bq + 3;
    int i8 = 32 + bq + 0,  i9 = 32 + bq + 1,  i10 = 32 + bq + 2, i11 = 32 + bq + 3;
    int i12 = 48 + bq + 0, i13 = 48 + bq + 1, i14 = 48 + bq + 2, i15 = 48 + bq + 3;

    float rm = -INFINITY;    // max of all rejected elements

    SORT8(e0,i0, e1,i1, e2,i2, e3,i3, e4,i4, e5,i5, e6,i6, e7,i7)
    SORT8(e8,i8, e9,i9, e10,i10, e11,i11, e12,i12, e13,i13, e14,i14, e15,i15)

    // intra-lane: top-8 of two sorted-8 lists (bitonic merge)
    MTOP(e0,i0, e15,i15) MTOP(e1,i1, e14,i14)
    MTOP(e2,i2, e13,i13) MTOP(e3,i3, e12,i12)
    MTOP(e4,i4, e11,i11) MTOP(e5,i5, e10,i10)
    MTOP(e6,i6, e9,i9)   MTOP(e7,i7, e8,i8)
    BITONIC8(e0,i0, e1,i1, e2,i2, e3,i3, e4,i4, e5,i5, e6,i6, e7,i7)

    MERGE_LEVEL(1)
    MERGE_LEVEL(2)

    if (!ok) return;    // all shuffles done; invalid quads exit together

    // ---- tie screen (unchanged semantics from the passing kernels) ----
    const float T = 1e-6f;
    bool tie = ((e0 - e1) <= T) | ((e1 - e2) <= T) | ((e2 - e3) <= T) |
               ((e3 - e4) <= T) | ((e4 - e5) <= T) | ((e5 - e6) <= T) |
               ((e6 - e7) <= T) | ((e7 - rm) <= T);

    float ce0, ce1, ce2, ce3, ce4, ce5, ce6, ce7;
    int   o0, o1, o2, o3, o4, o5, o6, o7;

    if (__builtin_expect(!tie, 1)) {
        ce0 = 1.0f;
        ce1 = __expf(e1 - e0); ce2 = __expf(e2 - e0);
        ce3 = __expf(e3 - e0); ce4 = __expf(e4 - e0);
        ce5 = __expf(e5 - e0); ce6 = __expf(e6 - e0);
        ce7 = __expf(e7 - e0);
        o0 = i0; o1 = i1; o2 = i2; o3 = i3;
        o4 = i4; o5 = i5; o6 = i6; o7 = i7;
    } else {
        // exact path (rare, exec-masked): re-read row, depth-10 stable
        // selection + correctly-rounded-exp tie ordering.
        const float* rowp = logits + (size_t)row * NEXP;
        float sv0 = -INFINITY, sv1 = -INFINITY, sv2 = -INFINITY, sv3 = -INFINITY;
        float sv4 = -INFINITY, sv5 = -INFINITY, sv6 = -INFINITY, sv7 = -INFINITY;
        float sv8 = -INFINITY, sv9 = -INFINITY;
        int   si0 = 0, si1 = 0, si2 = 0, si3 = 0, si4 = 0;
        int   si5 = 0, si6 = 0, si7 = 0, si8 = 0, si9 = 0;

        #pragma unroll 1
        for (int e = 0; e < NEXP; ++e) {
            float x = rowp[e]; int xi = e;
            SLOW_STAGE(sv0, si0)
            SLOW_STAGE(sv1, si1)
            SLOW_STAGE(sv2, si2)
            SLOW_STAGE(sv3, si3)
            SLOW_STAGE(sv4, si4)
            SLOW_STAGE(sv5, si5)
            SLOW_STAGE(sv6, si6)
            SLOW_STAGE(sv7, si7)
            SLOW_STAGE(sv8, si8)
            SLOW_STAGE(sv9, si9)
        }

        double m = (double)sv0;
        float s0 = (float)exp((double)sv0 - m);
        float s1 = (float)exp((double)sv1 - m);
        float s2 = (float)exp((double)sv2 - m);
        float s3 = (float)exp((double)sv3 - m);
        float s4 = (float)exp((double)sv4 - m);
        float s5 = (float)exp((double)sv5 - m);
        float s6 = (float)exp((double)sv6 - m);
        float s7 = (float)exp((double)sv7 - m);
        float s8 = (float)exp((double)sv8 - m);
        float s9 = (float)exp((double)sv9 - m);

        TIEPASS
        TIEPASS
        TIEPASS
        TIEPASS

        ce0 = s0; ce1 = s1; ce2 = s2; ce3 = s3;
        ce4 = s4; ce5 = s5; ce6 = s6; ce7 = s7;
        o0 = si0; o1 = si1; o2 = si2; o3 = si3;
        o4 = si4; o5 = si5; o6 = si6; o7 = si7;
    }

    float s = ((ce0 + ce1) + (ce2 + ce3)) + ((ce4 + ce5) + (ce6 + ce7));
    float r = 1.0f / s;

    // each lane stores ONE float4 by quarter-slot q:
    //   q=0 -> weights[0:4], q=1 -> weights[4:8], q=2 -> ids[0:4], q=3 -> ids[4:8]
    const bool hi  = (q & 1);
    const bool typ = (q >> 1);

    float4 outv;
    outv.x = typ ? (hi ? (float)o4 : (float)o0) : (hi ? ce4 * r : ce0 * r);
    outv.y = typ ? (hi ? (float)o5 : (float)o1) : (hi ? ce5 * r : ce1 * r);
    outv.z = typ ? (hi ? (float)o6 : (float)o2) : (hi ? ce6 * r : ce2 * r);
    outv.w = typ ? (hi ? (float)o7 : (float)o3) : (hi ? ce7 * r : ce3 * r);

    float* basep = typ ? id_out : w_out;
    float4* op = (float4*)(basep + (size_t)row * TOPK) + (hi ? 1 : 0);
    *op = outv;
}

// r13's quad structure, 32 rows per wave in TWO pipelined batches of 16.
// All 8 loads are issued FIRST and pinned with sched_barrier(0) so the
// compiler cannot sink batch-B loads below batch-A compute (the r15 failure,
// proven by VGPR collapsing to 44). Batch B's HBM latency hides under A's
// ~1900-cycle selection network. No LDS, no barriers, cached stores.
__global__ __launch_bounds__(256) void topk_router_kernel(
    const float* __restrict__ logits,
    float* __restrict__ w_out,      // [N,8] weights
    float* __restrict__ id_out,     // [N,8] ids stored as float values
    float* __restrict__ l_out,      // [N,64] passthrough copy
    int nrows)
{
    const int lane = threadIdx.x & 63;
    const int wv   = threadIdx.x >> 6;
    const int q    = lane & 3;          // quarter-slot within the row
    const int rloc = lane >> 2;         // row within batch 0..15
    const int rowBase = (blockIdx.x * 4 + wv) * 32;
    if (rowBase >= nrows) return;       // whole wave exits together

    const float4* __restrict__ src = (const float4*)logits;
    float4* __restrict__ dst       = (float4*)l_out;

    const int rowA = rowBase + rloc;
    const int rowB = rowBase + 16 + rloc;
    const bool okA = (rowA < nrows);
    const bool okB = (rowB < nrows);
    const size_t bA = (size_t)rowA * (NEXP / 4) + q;
    const size_t bB = (size_t)rowB * (NEXP / 4) + q;
    const float4 z = make_float4(0.f, 0.f, 0.f, 0.f);

    // issue ALL 8 loads up-front...
    float4 A0 = okA ? src[bA + 0]  : z;
    float4 A1 = okA ? src[bA + 4]  : z;
    float4 A2 = okA ? src[bA + 8]  : z;
    float4 A3 = okA ? src[bA + 12] : z;
    float4 B0 = okB ? src[bB + 0]  : z;
    float4 B1 = okB ? src[bB + 4]  : z;
    float4 B2 = okB ? src[bB + 8]  : z;
    float4 B3 = okB ? src[bB + 12] : z;
    // ...and pin them above everything that follows.
    __builtin_amdgcn_sched_barrier(0);

    // passthrough A (waits on A only), then compute A while B's loads fly
    if (okA) {
        dst[bA + 0] = A0; dst[bA + 4]  = A1;
        dst[bA + 8] = A2; dst[bA + 12] = A3;
    }

    process_rows(A0, A1, A2, A3, q, rowA, okA, logits, w_out, id_out);

    // passthrough B (first use of B regs), then compute B
    if (okB) {
        dst[bB + 0] = B0; dst[bB + 4]  = B1;
        dst[bB + 8] = B2; dst[bB + 12] = B3;
    }

    process_rows(B0, B1, B2, B3, q, rowB, okB, logits, w_out, id_out);
}

extern "C" void kernel_launch(void* const* d_in, const int* in_sizes, int n_in,
                              void* d_out, int out_size, void* d_ws, size_t ws_size,
                              hipStream_t stream) {
    const float* logits = (const float*)d_in[0];
    int nrows = in_sizes[0] / NEXP;

    float* out    = (float*)d_out;
    float* w_out  = out;
    float* id_out = out + (size_t)nrows * TOPK;
    float* l_out  = out + (size_t)nrows * 2 * TOPK;

    // 128 rows per block (4 waves x 32 rows), 256 threads
    int blocks = (nrows + 127) / 128;
    topk_router_kernel<<<blocks, 256, 0, stream>>>(logits, w_out, id_out, l_out, nrows);
}

// Round 17
// 125.270 us; speedup vs baseline: 1.4119x; 1.4119x over previous
//
#include <hip/hip_runtime.h>
#include <hip/hip_bf16.h>
#include <math.h>

#define NEXP 64
#define TOPK 8

// 4 lanes per row, 16 rows per wave, 4 independent waves per block.
// No LDS, no barriers, no transpose. Ownership mapping: lane (r,q)'s i-th
// float4 chunk = element range [i*16 + q*4, i*16 + q*4 + 4) -> per load/store
// instruction a quad covers a CONTIGUOUS 64B (2x line-touch amplification;
// measured best point: 124.9us. 1x amplification (r14) and halved VALU (r11)
// were both null; pipelining (r15/r16) regressed).
__global__ __launch_bounds__(256) void topk_router_kernel(
    const float* __restrict__ logits,
    float* __restrict__ w_out,      // [N,8] weights
    float* __restrict__ id_out,     // [N,8] ids stored as float values
    float* __restrict__ l_out,      // [N,64] passthrough copy
    int nrows)
{
    const int lane = threadIdx.x & 63;
    const int wv   = threadIdx.x >> 6;
    const int q    = lane & 3;          // quarter-slot of the row this lane owns
    const int rloc = lane >> 2;         // row within wave 0..15
    const int row  = (blockIdx.x * 4 + wv) * 16 + rloc;
    if (row >= nrows) return;           // whole 4-lane quads exit together

    // chunk i of this lane: float4 index row*16 + i*4 + q
    const float4* __restrict__ src = (const float4*)logits + (size_t)row * (NEXP / 4) + q;
    float4* __restrict__ dst       = (float4*)l_out  + (size_t)row * (NEXP / 4) + q;

    float4 a0 = src[0], a1 = src[4], a2 = src[8], a3 = src[12];
    dst[0] = a0; dst[4] = a1; dst[8] = a2; dst[12] = a3;

    // element indices: chunk i covers i*16 + q*4 + {0,1,2,3}
    const int b0 = q * 4;
    float e0 = a0.x,  e1 = a0.y,  e2 = a0.z,  e3 = a0.w;
    float e4 = a1.x,  e5 = a1.y,  e6 = a1.z,  e7 = a1.w;
    float e8 = a2.x,  e9 = a2.y,  e10 = a2.z, e11 = a2.w;
    float e12 = a3.x, e13 = a3.y, e14 = a3.z, e15 = a3.w;
    int i0 = b0 + 0,       i1 = b0 + 1,       i2 = b0 + 2,       i3 = b0 + 3;
    int i4 = 16 + b0 + 0,  i5 = 16 + b0 + 1,  i6 = 16 + b0 + 2,  i7 = 16 + b0 + 3;
    int i8 = 32 + b0 + 0,  i9 = 32 + b0 + 1,  i10 = 32 + b0 + 2, i11 = 32 + b0 + 3;
    int i12 = 48 + b0 + 0, i13 = 48 + b0 + 1, i14 = 48 + b0 + 2, i15 = 48 + b0 + 3;

    float rm = -INFINITY;    // max of all rejected elements

    // compare-exchange, descending, strict (> only): equal values never swap
#define CE(VA, IA, VB, IB)                                        \
    {                                                             \
        bool s_ = ((VB) > (VA));                                  \
        float tv_ = (VA); int ti_ = (IA);                         \
        VA = s_ ? (VB) : (VA); IA = s_ ? (IB) : (IA);             \
        VB = s_ ? tv_  : (VB); IB = s_ ? ti_  : (IB);             \
    }

    // Batcher odd-even merge sort for 8 (19 CE), descending
#define SORT8(V0,I0,V1,I1,V2,I2,V3,I3,V4,I4,V5,I5,V6,I6,V7,I7)        \
    CE(V0,I0,V1,I1) CE(V2,I2,V3,I3) CE(V4,I4,V5,I5) CE(V6,I6,V7,I7)   \
    CE(V0,I0,V2,I2) CE(V1,I1,V3,I3) CE(V4,I4,V6,I6) CE(V5,I5,V7,I7)   \
    CE(V1,I1,V2,I2) CE(V5,I5,V6,I6)                                   \
    CE(V0,I0,V4,I4) CE(V1,I1,V5,I5) CE(V2,I2,V6,I6) CE(V3,I3,V7,I7)   \
    CE(V2,I2,V4,I4) CE(V3,I3,V5,I5)                                   \
    CE(V1,I1,V2,I2) CE(V3,I3,V4,I4) CE(V5,I5,V6,I6)

    SORT8(e0,i0, e1,i1, e2,i2, e3,i3, e4,i4, e5,i5, e6,i6, e7,i7)
    SORT8(e8,i8, e9,i9, e10,i10, e11,i11, e12,i12, e13,i13, e14,i14, e15,i15)

    // winner/loser step: VA <- max(VA,VB), rm <- max(rm, loser)
#define MTOP(VA, IA, VB, IB)                                      \
    {                                                             \
        bool s_ = ((VB) > (VA));                                  \
        float lo_ = s_ ? (VA) : (VB);                             \
        VA = s_ ? (VB) : (VA); IA = s_ ? (IB) : (IA);             \
        rm = fmaxf(rm, lo_);                                      \
    }

    // bitonic clean of a descending-bitonic 8 (12 CE)
#define BITONIC8(V0,I0,V1,I1,V2,I2,V3,I3,V4,I4,V5,I5,V6,I6,V7,I7)     \
    CE(V0,I0,V4,I4) CE(V1,I1,V5,I5) CE(V2,I2,V6,I6) CE(V3,I3,V7,I7)   \
    CE(V0,I0,V2,I2) CE(V1,I1,V3,I3) CE(V4,I4,V6,I6) CE(V5,I5,V7,I7)   \
    CE(V0,I0,V1,I1) CE(V2,I2,V3,I3) CE(V4,I4,V5,I5) CE(V6,I6,V7,I7)

    // intra-lane: top-8 of two sorted-8 lists (bitonic merge)
    MTOP(e0,i0, e15,i15) MTOP(e1,i1, e14,i14)
    MTOP(e2,i2, e13,i13) MTOP(e3,i3, e12,i12)
    MTOP(e4,i4, e11,i11) MTOP(e5,i5, e10,i10)
    MTOP(e6,i6, e9,i9)   MTOP(e7,i7, e8,i8)
    BITONIC8(e0,i0, e1,i1, e2,i2, e3,i3, e4,i4, e5,i5, e6,i6, e7,i7)

    // cross-lane merge: partner's sorted-8 reversed feeds the bitonic merge
#define MERGE_LEVEL(MASK)                                                     \
    {                                                                         \
        float b0_ = __shfl_xor(e0, MASK), b1_ = __shfl_xor(e1, MASK);         \
        float b2_ = __shfl_xor(e2, MASK), b3_ = __shfl_xor(e3, MASK);         \
        float b4_ = __shfl_xor(e4, MASK), b5_ = __shfl_xor(e5, MASK);         \
        float b6_ = __shfl_xor(e6, MASK), b7_ = __shfl_xor(e7, MASK);         \
        int   j0_ = __shfl_xor(i0, MASK), j1_ = __shfl_xor(i1, MASK);         \
        int   j2_ = __shfl_xor(i2, MASK), j3_ = __shfl_xor(i3, MASK);         \
        int   j4_ = __shfl_xor(i4, MASK), j5_ = __shfl_xor(i5, MASK);         \
        int   j6_ = __shfl_xor(i6, MASK), j7_ = __shfl_xor(i7, MASK);         \
        float pr_ = __shfl_xor(rm, MASK);                                     \
        rm = fmaxf(rm, pr_);                                                  \
        MTOP(e0,i0, b7_,j7_) MTOP(e1,i1, b6_,j6_)                             \
        MTOP(e2,i2, b5_,j5_) MTOP(e3,i3, b4_,j4_)                             \
        MTOP(e4,i4, b3_,j3_) MTOP(e5,i5, b2_,j2_)                             \
        MTOP(e6,i6, b1_,j1_) MTOP(e7,i7, b0_,j0_)                             \
        BITONIC8(e0,i0, e1,i1, e2,i2, e3,i3, e4,i4, e5,i5, e6,i6, e7,i7)      \
    }

    MERGE_LEVEL(1)
    MERGE_LEVEL(2)

    // ---- tie screen: any equality/near-tie involving a selected element or
    // the 8/9 boundary lands adjacent here (lists are sorted); gap<=T -> slow.
    const float T = 1e-6f;
    bool tie = ((e0 - e1) <= T) | ((e1 - e2) <= T) | ((e2 - e3) <= T) |
               ((e3 - e4) <= T) | ((e4 - e5) <= T) | ((e5 - e6) <= T) |
               ((e6 - e7) <= T) | ((e7 - rm) <= T);

    float ce0, ce1, ce2, ce3, ce4, ce5, ce6, ce7;
    int   o0, o1, o2, o3, o4, o5, o6, o7;

    if (__builtin_expect(!tie, 1)) {
        // fast path: no representable score tie possible
        ce0 = 1.0f;
        ce1 = __expf(e1 - e0); ce2 = __expf(e2 - e0);
        ce3 = __expf(e3 - e0); ce4 = __expf(e4 - e0);
        ce5 = __expf(e5 - e0); ce6 = __expf(e6 - e0);
        ce7 = __expf(e7 - e0);
        o0 = i0; o1 = i1; o2 = i2; o3 = i3;
        o4 = i4; o5 = i5; o6 = i6; o7 = i7;
    } else {
        // exact path (rare, exec-masked, deterministic per row): re-read the
        // row, depth-10 stable selection + correctly-rounded-exp tie order.
        const float* rowp = logits + (size_t)row * NEXP;
        float sv0 = -INFINITY, sv1 = -INFINITY, sv2 = -INFINITY, sv3 = -INFINITY;
        float sv4 = -INFINITY, sv5 = -INFINITY, sv6 = -INFINITY, sv7 = -INFINITY;
        float sv8 = -INFINITY, sv9 = -INFINITY;
        int   si0 = 0, si1 = 0, si2 = 0, si3 = 0, si4 = 0;
        int   si5 = 0, si6 = 0, si7 = 0, si8 = 0, si9 = 0;

#define SLOW_STAGE(TV, TI)                                \
    {                                                     \
        bool gt = (x > TV);                               \
        float nv = gt ? x  : TV;                          \
        float cv = gt ? TV : x;                           \
        int   ni = gt ? xi : TI;                          \
        int   ci = gt ? TI : xi;                          \
        TV = nv; x = cv; TI = ni; xi = ci;                \
    }

        #pragma unroll 1
        for (int e = 0; e < NEXP; ++e) {
            float x = rowp[e]; int xi = e;
            SLOW_STAGE(sv0, si0)
            SLOW_STAGE(sv1, si1)
            SLOW_STAGE(sv2, si2)
            SLOW_STAGE(sv3, si3)
            SLOW_STAGE(sv4, si4)
            SLOW_STAGE(sv5, si5)
            SLOW_STAGE(sv6, si6)
            SLOW_STAGE(sv7, si7)
            SLOW_STAGE(sv8, si8)
            SLOW_STAGE(sv9, si9)
        }

        double m = (double)sv0;
        float s0 = (float)exp((double)sv0 - m);
        float s1 = (float)exp((double)sv1 - m);
        float s2 = (float)exp((double)sv2 - m);
        float s3 = (float)exp((double)sv3 - m);
        float s4 = (float)exp((double)sv4 - m);
        float s5 = (float)exp((double)sv5 - m);
        float s6 = (float)exp((double)sv6 - m);
        float s7 = (float)exp((double)sv7 - m);
        float s8 = (float)exp((double)sv8 - m);
        float s9 = (float)exp((double)sv9 - m);

#define TIESWAP(CA, IA, CB, IB)                           \
    {                                                     \
        bool sw = (CA == CB) && (IA > IB);                \
        int tt = IA;                                      \
        IA = sw ? IB : IA;                                \
        IB = sw ? tt : IB;                                \
    }
#define TIEPASS                                           \
    TIESWAP(s0, si0, s1, si1)                             \
    TIESWAP(s1, si1, s2, si2)                             \
    TIESWAP(s2, si2, s3, si3)                             \
    TIESWAP(s3, si3, s4, si4)                             \
    TIESWAP(s4, si4, s5, si5)                             \
    TIESWAP(s5, si5, s6, si6)                             \
    TIESWAP(s6, si6, s7, si7)                             \
    TIESWAP(s7, si7, s8, si8)                             \
    TIESWAP(s8, si8, s9, si9)

        TIEPASS
        TIEPASS
        TIEPASS
        TIEPASS

        ce0 = s0; ce1 = s1; ce2 = s2; ce3 = s3;
        ce4 = s4; ce5 = s5; ce6 = s6; ce7 = s7;
        o0 = si0; o1 = si1; o2 = si2; o3 = si3;
        o4 = si4; o5 = si5; o6 = si6; o7 = si7;
    }

    float s = ((ce0 + ce1) + (ce2 + ce3)) + ((ce4 + ce5) + (ce6 + ce7));
    float r = 1.0f / s;

    // ---- each lane stores ONE float4, selected by its quarter-slot q:
    //   q=0 -> weights[0:4], q=1 -> weights[4:8], q=2 -> ids[0:4], q=3 -> ids[4:8]
    // wave footprint: 512B contiguous in w_out + 512B contiguous in id_out.
    const bool hi  = (q & 1);
    const bool typ = (q >> 1);      // 0 = weights, 1 = ids

    float4 outv;
    outv.x = typ ? (hi ? (float)o4 : (float)o0) : (hi ? ce4 * r : ce0 * r);
    outv.y = typ ? (hi ? (float)o5 : (float)o1) : (hi ? ce5 * r : ce1 * r);
    outv.z = typ ? (hi ? (float)o6 : (float)o2) : (hi ? ce6 * r : ce2 * r);
    outv.w = typ ? (hi ? (float)o7 : (float)o3) : (hi ? ce7 * r : ce3 * r);

    float* basep = typ ? id_out : w_out;
    float4* op = (float4*)(basep + (size_t)row * TOPK) + (hi ? 1 : 0);
    *op = outv;
}

extern "C" void kernel_launch(void* const* d_in, const int* in_sizes, int n_in,
                              void* d_out, int out_size, void* d_ws, size_t ws_size,
                              hipStream_t stream) {
    const float* logits = (const float*)d_in[0];
    int nrows = in_sizes[0] / NEXP;

    float* out    = (float*)d_out;
    float* w_out  = out;
    float* id_out = out + (size_t)nrows * TOPK;
    float* l_out  = out + (size_t)nrows * 2 * TOPK;

    // 64 rows per block (4 waves x 16 rows), 256 threads
    int blocks = (nrows + 63) / 64;
    topk_router_kernel<<<blocks, 256, 0, stream>>>(logits, w_out, id_out, l_out, nrows);
}